// Round 13
// baseline (199.066 us; speedup 1.0000x reference)
//
#include <hip/hip_runtime.h>
#include <math.h>

#define BATCH   16384
#define HD      24      // LSTM hidden size
#define NOUTC   24
#define NHID    16
#define NSTEPS  47
#define NG      96
#define GRP     32      // elements per block (2 per thread)
#define NTG     12      // thread-groups per element
#define JPW     2       // j-slots per thread-group
#define GPW     8       // gates per thread-group
#define THREADS 192     // NTG * GRP/2, 3 waves; grid 512 -> 4 blocks/CU

__device__ __forceinline__ float fast_sigmoid(float x) {
    float t = __expf(-x);
    return __builtin_amdgcn_rcpf(1.0f + t);
}
__device__ __forceinline__ float fast_tanh(float x) {
    float ax = fabsf(x);
    float t  = __expf(-2.0f * ax);
    float r  = (1.0f - t) * __builtin_amdgcn_rcpf(1.0f + t);
    return copysignf(r, x);
}

__global__ __launch_bounds__(THREADS) void policy_kernel(
    const float* __restrict__ W_ih, const float* __restrict__ W_hh,
    const float* __restrict__ b_ih, const float* __restrict__ b_hh,
    const float* __restrict__ Wl,   const float* __restrict__ bl,
    const float* __restrict__ rnd,  float* __restrict__ out)
{
    __shared__ float sWihB[NG][25];          // [g][c] + bias folded
    __shared__ float sBias[NG];              // b_ih + b_hh (step 0)
    __shared__ float sWhhP[HD][NTG][GPW];    // [k][w][t*2+i] : gate g = t*24 + w*2 + i
    __shared__ float sWlP[HD][NTG][JPW];     // [k][w][i] : logit col n = w*2+i
    __shared__ float sBl[NOUTC];
    __shared__ float hh[HD][GRP];            // single h buffer (reads/writes barrier-separated)
    __shared__ float sLt[GRP][28];           // transposed logits exchange
    __shared__ float sPr[GRP][NSTEPS + 2];
    __shared__ unsigned char sAct8[GRP][NSTEPS + 2];

    const int tid = threadIdx.x;
    const int w   = tid >> 4;                // thread-group 0..11
    const int e   = tid & 15;                // element-pair index: owns elements 2e, 2e+1
    const int b0  = blockIdx.x * GRP + 2 * e;

    // ---- staging (once per block) ----
    for (int i = tid; i < NG * HD; i += THREADS) {
        int g = i / HD, k = i % HD;
        float bs = b_ih[g] + b_hh[g];
        sWihB[g][k] = W_ih[i] + bs;
        int t = g / 24, rem = g % 24;
        sWhhP[k][rem >> 1][t * JPW + (rem & 1)] = W_hh[i];
    }
    for (int i = tid; i < NOUTC * HD; i += THREADS) {
        int n = i / HD, k = i % HD;
        sWlP[k][n >> 1][n & 1] = Wl[i];
    }
    if (tid < NG)    sBias[tid] = b_ih[tid] + b_hh[tid];
    if (tid < NOUTC) sBl[tid]   = bl[tid];
    for (int i = tid; i < HD * GRP; i += THREADS) (&hh[0][0])[i] = 0.f;
    __syncthreads();

    float cst0[JPW] = {0.f, 0.f};
    float cst1[JPW] = {0.f, 0.f};
    float accN0[GPW], accN1[GPW];            // GEMV partials (h-term); h0=0 -> exactly 0
    #pragma unroll
    for (int q = 0; q < GPW; ++q) { accN0[q] = 0.f; accN1[q] = 0.f; }
    int act0 = 0, act1 = 0;

    for (int s = 0; s < NSTEPS; ++s) {
        const float2 r2 = *(const float2*)&rnd[s * BATCH + b0];  // issue early

        // ---- complete gates: acc = GEMV-partial + gather row (bias folded) ----
        float a0[GPW], a1[GPW];
        if (s == 0) {
            #pragma unroll
            for (int t = 0; t < 4; ++t)
                #pragma unroll
                for (int i = 0; i < JPW; ++i) {
                    float bb = sBias[t * 24 + w * JPW + i];
                    a0[t * JPW + i] = accN0[t * JPW + i] + bb;
                    a1[t * JPW + i] = accN1[t * JPW + i] + bb;
                }
        } else {
            #pragma unroll
            for (int t = 0; t < 4; ++t)
                #pragma unroll
                for (int i = 0; i < JPW; ++i) {
                    int g = t * 24 + w * JPW + i;
                    a0[t * JPW + i] = accN0[t * JPW + i] + sWihB[g][act0];
                    a1[t * JPW + i] = accN1[t * JPW + i] + sWihB[g][act1];
                }
        }

        // ---- LSTM cell for own 2 j's × 2 elements; h pair written as float2 ----
        #pragma unroll
        for (int i = 0; i < JPW; ++i) {
            float si0 = fast_sigmoid(a0[i]);
            float sf0 = fast_sigmoid(a0[JPW + i]);
            float so0 = fast_sigmoid(a0[3 * JPW + i]);
            float tg0 = fast_tanh(a0[2 * JPW + i]);
            float cj0 = sf0 * cst0[i] + si0 * tg0;
            cst0[i] = cj0;
            float si1 = fast_sigmoid(a1[i]);
            float sf1 = fast_sigmoid(a1[JPW + i]);
            float so1 = fast_sigmoid(a1[3 * JPW + i]);
            float tg1 = fast_tanh(a1[2 * JPW + i]);
            float cj1 = sf1 * cst1[i] + si1 * tg1;
            cst1[i] = cj1;
            float2 hv = make_float2(so0 * fast_tanh(cj0), so1 * fast_tanh(cj1));
            *(float2*)&hh[w * JPW + i][2 * e] = hv;
        }
        __syncthreads();   // B: new h visible

        // ---- merged k-loop: logits(s) + gates-GEMV(s+1); weights shared by both elements ----
        float l00 = 0.f, l01 = 0.f, l10 = 0.f, l11 = 0.f;
        #pragma unroll
        for (int q = 0; q < GPW; ++q) { accN0[q] = 0.f; accN1[q] = 0.f; }
        #pragma unroll 4
        for (int k = 0; k < HD; ++k) {
            float2 hk = *(const float2*)&hh[k][2 * e];     // both elements, one b64
            const float* wp = &sWhhP[k][w][0];
            float4 w0 = *(const float4*)&wp[0];
            float4 w1 = *(const float4*)&wp[4];
            float2 lv = *(const float2*)&sWlP[k][w][0];
            accN0[0] = fmaf(hk.x, w0.x, accN0[0]);  accN1[0] = fmaf(hk.y, w0.x, accN1[0]);
            accN0[1] = fmaf(hk.x, w0.y, accN0[1]);  accN1[1] = fmaf(hk.y, w0.y, accN1[1]);
            accN0[2] = fmaf(hk.x, w0.z, accN0[2]);  accN1[2] = fmaf(hk.y, w0.z, accN1[2]);
            accN0[3] = fmaf(hk.x, w0.w, accN0[3]);  accN1[3] = fmaf(hk.y, w0.w, accN1[3]);
            accN0[4] = fmaf(hk.x, w1.x, accN0[4]);  accN1[4] = fmaf(hk.y, w1.x, accN1[4]);
            accN0[5] = fmaf(hk.x, w1.y, accN0[5]);  accN1[5] = fmaf(hk.y, w1.y, accN1[5]);
            accN0[6] = fmaf(hk.x, w1.z, accN0[6]);  accN1[6] = fmaf(hk.y, w1.z, accN1[6]);
            accN0[7] = fmaf(hk.x, w1.w, accN0[7]);  accN1[7] = fmaf(hk.y, w1.w, accN1[7]);
            l00 = fmaf(hk.x, lv.x, l00);            l10 = fmaf(hk.y, lv.x, l10);
            l01 = fmaf(hk.x, lv.y, l01);            l11 = fmaf(hk.y, lv.y, l11);
        }
        {
            float bl0 = sBl[w * JPW + 0], bl1 = sBl[w * JPW + 1];
            *(float2*)&sLt[2 * e + 0][w * JPW] = make_float2(l00 + bl0, l01 + bl1);
            *(float2*)&sLt[2 * e + 1][w * JPW] = make_float2(l10 + bl0, l11 + bl1);
        }
        __syncthreads();   // C: logits visible

        // ---- redundant in-register finish, element 0 then element 1 (scoped) ----
        const int  cnt = (s + 1) >> 1;
        const bool odd = (s & 1) != 0;
        #pragma unroll
        for (int elem = 0; elem < 2; ++elem) {
            const float r = (elem == 0) ? r2.x : r2.y;
            const int   ee = 2 * e + elem;
            float v[NOUTC];
            #pragma unroll
            for (int n4 = 0; n4 < 6; ++n4) {
                float4 vv = *(const float4*)&sLt[ee][n4 * 4];
                v[n4 * 4 + 0] = vv.x; v[n4 * 4 + 1] = vv.y;
                v[n4 * 4 + 2] = vv.z; v[n4 * 4 + 3] = vv.w;
            }
            float Z = 0.f, cum = 0.f, ea = 0.f, m = -INFINITY;
            int a = 0;
            bool found = false;
            if (odd) {
                #pragma unroll
                for (int n = 0; n < NOUTC; ++n) m = fmaxf(m, (n < cnt) ? v[n] : -INFINITY);
                #pragma unroll
                for (int n = 0; n < NOUTC; ++n) v[n] = (n < cnt) ? __expf(v[n] - m) : 0.f;
                #pragma unroll
                for (int n = 0; n < NOUTC; ++n) Z += v[n];
                const float rZ = r * Z;
                #pragma unroll
                for (int n = 0; n < NOUTC; ++n) {
                    cum += v[n];
                    if (!found && cum > rZ) { found = true; a = n; ea = v[n]; }
                }
                if (!found) { a = 0; ea = v[0]; }
            } else {
                #pragma unroll
                for (int n = NHID; n < NOUTC; ++n) m = fmaxf(m, v[n]);
                #pragma unroll
                for (int n = NHID; n < NOUTC; ++n) v[n] = __expf(v[n] - m);
                #pragma unroll
                for (int n = NHID; n < NOUTC; ++n) Z += v[n];
                const float rZ = r * Z;
                #pragma unroll
                for (int n = NHID; n < NOUTC; ++n) {
                    cum += v[n];
                    if (!found && cum > rZ) { found = true; a = n; ea = v[n]; }
                }
                if (!found) { a = 0; ea = 0.f; }    // ref: p[0]=0 on even steps
            }
            float pr = ea / Z;                      // IEEE div, mirrors reference
            if (w == 0) { sPr[ee][s] = pr; sAct8[ee][s] = (unsigned char)a; }
            if (elem == 0) act0 = a; else act1 = a;
        }
    }

    __syncthreads();
    // ---- coalesced write-out ----
    const int base = blockIdx.x * GRP * NSTEPS;
    for (int i = tid; i < GRP * NSTEPS; i += THREADS) {
        int rr = i / NSTEPS, ss = i - rr * NSTEPS;
        out[base + i]                          = sPr[rr][ss];
        out[(size_t)BATCH * NSTEPS + base + i] = (float)sAct8[rr][ss];
    }
}

extern "C" void kernel_launch(void* const* d_in, const int* in_sizes, int n_in,
                              void* d_out, int out_size, void* d_ws, size_t ws_size,
                              hipStream_t stream) {
    const float* W_ih = (const float*)d_in[0];
    const float* W_hh = (const float*)d_in[1];
    const float* b_ih = (const float*)d_in[2];
    const float* b_hh = (const float*)d_in[3];
    const float* Wl   = (const float*)d_in[4];
    const float* bl   = (const float*)d_in[5];
    const float* rnd  = (const float*)d_in[6];
    float* o = (float*)d_out;

    policy_kernel<<<BATCH / GRP, THREADS, 0, stream>>>(W_ih, W_hh, b_ih, b_hh, Wl, bl, rnd, o);
}